// Round 3
// baseline (222.966 us; speedup 1.0000x reference)
//
#include <hip/hip_runtime.h>
#include <hip/hip_fp16.h>

// VectorBasis R15. Structural: phase2's entire sort/rank machinery replaced
// by ds_add_f32 LDS atomics. Mechanism: R13's regression isolated phase2
// block time at ~22us vs a ~5us memory floor -- the gap was per-chunk rid/
// gather/histogram/scan/scatter/imbalanced-accumulate + ~15 barriers, all of
// which existed only to avoid atomics. gfx950 ds_add_f32 makes the per-bin
// accumulate ~288 wave-instrs (negligible), so:
//  - phase1 keeps the proven LDS bin-sort but reserves a contiguous per-bin
//    range in a BIN-MAJOR global payload (one atomicAdd(gcnt[bin],cnt) per
//    non-empty bin per block) and scatters its sorted runs there. The 42B-
//    run coalescing loss moves from phase2-read to phase1-write; the runoff
//    table (1.3MB + per-bin 782-row scans) disappears.
//  - phase2: stream the contiguous per-bin segment (coalesced dwordx4),
//    unpack fp16 pairs, 9x atomicAdd into a 4.5KB LDS tile, write out.
//    2 barriers, 8 blocks/CU (was 4 at 39.8KB LDS).
// BSTR=2560 is ~11 sigma above the binomial per-bin mean (2048); slot guard
// drops (never corrupts) on adversarial distributions. ds_add order is
// non-deterministic -> fp jitter << fp16 record quantization (absmax 2^-7).
// Fixed harness overhead (~90us ws-poison fills) bounds the wall from below.

constexpr int NSP  = 4;
constexpr int NRAD = 8;
constexpr int NPS  = 4;
constexpr int DDIM = NRAD * NPS;       // 32

constexpr int APB       = 128;         // atoms per bin
constexpr int APB_SH    = 7;
constexpr int NBIN_PAD  = 832;         // 64*13 >= nbin(782)
constexpr int PH1_BLK   = 512;
constexpr int PH1_U     = 4;
constexpr int PH1_REC   = PH1_BLK * PH1_U;  // 2048
constexpr int BSTR      = 2560;        // per-bin payload capacity (records)

__device__ __forceinline__ unsigned pack2(float a, float b) {
    union { __half2 h; unsigned u; } cv;
    cv.h = __floats2half2_rn(a, b);
    return cv.u;
}
__device__ __forceinline__ float2 unpack2(unsigned u) {
    union { unsigned u; __half2 h; } cv;
    cv.u = u;
    return __half22float2(cv.h);
}

__device__ __forceinline__ void build_w2(
    float* sW2, const float* cemb, const float* Wc, const float* W_alch,
    int tid, int nthreads)
{
    for (int i = tid; i < 3 * NRAD * 16; i += nthreads) {
        int p  = i & 15;
        int n  = (i >> 4) & 7;
        int o  = i >> 7;
        int sc = p >> 2, sn = p & 3;
        float w = 0.0f;
        #pragma unroll
        for (int q = 0; q < NPS; q++)
            w += cemb[sc * DDIM + n * NPS + q] * Wc[o * DDIM + n * NPS + q]
               * W_alch[sn * NPS + q];
        sW2[i] = w;
    }
}

__device__ __forceinline__ bool edge_math(
    float vx, float vy, float vz, int pair, const float* sW2,
    float g[3], float t[3])
{
    float d2    = vx * vx + vy * vy + vz * vz + 1e-12f;
    float d     = sqrtf(d2);
    float inv_d = 1.0f / d;

    const float PI = 3.14159265358979323846f;
    const float RCUT = 5.0f, INNER = 4.5f, INVW = 2.0f;
    if (d >= RCUT) return false;
    float taper = 0.5f * (__cosf(PI * (d - INNER) * INVW) + 1.0f);
    float fc = (d < INNER) ? 1.0f : taper;

    float theta = (PI / RCUT) * d;
    float s1 = __sinf(theta);
    float c1 = __cosf(theta);
    float two_c = 2.0f * c1;
    float R[NRAD];
    R[0] = s1 * inv_d;
    float sm2 = 0.0f, sm1 = s1;
    #pragma unroll
    for (int n = 1; n < NRAD; n++) {
        float s = two_c * sm1 - sm2;
        sm2 = sm1; sm1 = s;
        R[n] = s * inv_d;
    }

    #pragma unroll
    for (int o = 0; o < 3; o++) {
        float acc = 0.0f;
        #pragma unroll
        for (int n = 0; n < NRAD; n++)
            acc += R[n] * sW2[(o * NRAD + n) * 16 + pair];
        t[o] = acc;
    }
    g[0] = fc * vy * inv_d;
    g[1] = fc * vz * inv_d;
    g[2] = fc * vx * inv_d;
    return true;
}

// ====== phase1: block-private sort, per-bin global reservation, scatter =====
__global__ __launch_bounds__(PH1_BLK) void vb_phase1(
    const float* __restrict__ vecs,
    const int*   __restrict__ centers,
    const int*   __restrict__ neighbors,
    const int*   __restrict__ species,
    const float* __restrict__ W_alch,
    const float* __restrict__ cemb,
    const float* __restrict__ Wc,
    unsigned*    __restrict__ gcnt,       // (nbin) zeroed before launch
    int4*        __restrict__ payload,    // (nbin, BSTR) bin-major
    int E, int nbin)
{
    __shared__ float sW2[3 * NRAD * 16];        // 1.5 KB
    __shared__ int4  srec[PH1_REC];             // 32 KB
    __shared__ unsigned lcntP[NBIN_PAD / 2];    // 1.66 KB packed u16 pairs
    __shared__ unsigned short lexcl[NBIN_PAD];  // 1.66 KB
    __shared__ unsigned short gbase[NBIN_PAD];  // 1.66 KB  (base < BSTR fits u16)
    __shared__ int sTotal;                      // ~38.6 KB -> 4 blocks/CU

    int tid = threadIdx.x;
    build_w2(sW2, cemb, Wc, W_alch, tid, PH1_BLK);
    for (int i = tid; i < NBIN_PAD / 2; i += PH1_BLK) lcntP[i] = 0;
    __syncthreads();

    int4 rec[PH1_U];
    int  rnk[PH1_U];   // static indices only — stays in VGPRs
    #pragma unroll
    for (int u = 0; u < PH1_U; u++) {
        int e = blockIdx.x * PH1_REC + u * PH1_BLK + tid;
        rec[u].x = -1;
        rnk[u]   = 0;
        if (e < E) {
            float vx = vecs[3 * e + 0];
            float vy = vecs[3 * e + 1];
            float vz = vecs[3 * e + 2];
            int c  = centers[e];
            int pair = species[c] * 4 + species[neighbors[e]];
            float g[3], t[3];
            if (edge_math(vx, vy, vz, pair, sW2, g, t)) {
                rec[u].x = c;
                rec[u].y = (int)pack2(g[0], g[1]);
                rec[u].z = (int)pack2(g[2], t[0]);
                rec[u].w = (int)pack2(t[1], t[2]);
                int bin = c >> APB_SH;
                int sh  = (bin & 1) << 4;
                unsigned old = atomicAdd(&lcntP[bin >> 1], 1u << sh);
                rnk[u] = (int)((old >> sh) & 0xffff);   // arrival rank in bin
            }
        }
    }
    __syncthreads();

    // single-wave exclusive scan over NBIN_PAD bins (13/lane), packed counts
    if (tid < 64) {
        int base = tid * 13;
        int pre[13];
        int sum = 0;
        #pragma unroll
        for (int j = 0; j < 13; j++) {
            int b = base + j;
            int n = (lcntP[b >> 1] >> ((b & 1) << 4)) & 0xffff;
            pre[j] = sum; sum += n;
        }
        int incl = sum;
        #pragma unroll
        for (int off = 1; off < 64; off <<= 1) {
            int t = __shfl_up(incl, off, 64);
            if (tid >= off) incl += t;
        }
        int ex = incl - sum;
        #pragma unroll
        for (int j = 0; j < 13; j++)
            lexcl[base + j] = (unsigned short)(ex + pre[j]);
        if (tid == 63) sTotal = incl;
    }
    __syncthreads();

    // scatter records into LDS sorted by bin — NO atomic (slot = excl + rank)
    #pragma unroll
    for (int u = 0; u < PH1_U; u++) {
        if (rec[u].x >= 0) {
            int bin = rec[u].x >> APB_SH;
            srec[(int)lexcl[bin] + rnk[u]] = rec[u];
        }
    }

    // reserve contiguous per-bin ranges in the global bin-major payload
    // (counts still live in lcntP; one global atomic per non-empty bin)
    for (int b = tid; b < nbin; b += PH1_BLK) {
        int n = (int)((lcntP[b >> 1] >> ((b & 1) << 4)) & 0xffff);
        if (n) gbase[b] = (unsigned short)atomicAdd(&gcnt[b], (unsigned)n);
    }
    __syncthreads();

    // dump sorted runs to reserved ranges (runs avg ~2.6 rec = 42B segments)
    int total = sTotal;
    for (int i = tid; i < total; i += PH1_BLK) {
        int4 r  = srec[i];
        int bin = r.x >> APB_SH;
        int slot = (int)gbase[bin] + (i - (int)lexcl[bin]);
        if (slot < BSTR)                       // 11-sigma guard, never OOB
            payload[(size_t)bin * BSTR + slot] = r;
    }
}

// ====== phase2: stream contiguous bin segment, ds_add_f32 accumulate ========
__global__ __launch_bounds__(256) void vb_phase2(
    const unsigned* __restrict__ gcnt,
    const int4*     __restrict__ payload,    // (nbin, BSTR)
    float*          __restrict__ out,        // (A,9), fully overwritten
    int A)
{
    __shared__ float sout[APB * 9];          // 4.5 KB -> 8 blocks/CU

    int b   = blockIdx.x;
    int tid = threadIdx.x;

    for (int i = tid; i < APB * 9; i += 256) sout[i] = 0.0f;
    __syncthreads();

    int n = min((int)gcnt[b], BSTR);
    const int4* seg = payload + (size_t)b * BSTR;
    for (int i = tid; i < n; i += 256) {
        int4 r = seg[i];                     // coalesced dwordx4 stream
        int atom = r.x & (APB - 1);
        float2 g01 = unpack2((unsigned)r.y);
        float2 g2t = unpack2((unsigned)r.z);
        float2 t12 = unpack2((unsigned)r.w);
        float g0 = g01.x, g1 = g01.y, g2 = g2t.x;
        float t0 = g2t.y, t1 = t12.x, t2 = t12.y;
        float* s = &sout[atom * 9];
        atomicAdd(s + 0, g0 * t0); atomicAdd(s + 1, g0 * t1); atomicAdd(s + 2, g0 * t2);
        atomicAdd(s + 3, g1 * t0); atomicAdd(s + 4, g1 * t1); atomicAdd(s + 5, g1 * t2);
        atomicAdd(s + 6, g2 * t0); atomicAdd(s + 7, g2 * t1); atomicAdd(s + 8, g2 * t2);
    }
    __syncthreads();

    size_t gbase2 = (size_t)b * APB * 9;
    size_t lim = (size_t)A * 9;
    for (int i = tid; i < APB * 9; i += 256) {
        size_t gi = gbase2 + i;
        if (gi < lim) out[gi] = sout[i];
    }
}

// Fallback: direct per-edge global atomics (correct, slow).
__global__ __launch_bounds__(256) void vb_edge_fallback(
    const float* __restrict__ vecs,
    const int*   __restrict__ centers,
    const int*   __restrict__ neighbors,
    const int*   __restrict__ species,
    const float* __restrict__ W_alch,
    const float* __restrict__ cemb,
    const float* __restrict__ Wc,
    float*       __restrict__ out,
    int E)
{
    __shared__ float sW2[3 * NRAD * 16];
    build_w2(sW2, cemb, Wc, W_alch, threadIdx.x, blockDim.x);
    __syncthreads();

    int e = blockIdx.x * blockDim.x + threadIdx.x;
    if (e >= E) return;
    float vx = vecs[3 * e + 0], vy = vecs[3 * e + 1], vz = vecs[3 * e + 2];
    int c = centers[e];
    int pair = species[c] * 4 + species[neighbors[e]];
    float g[3], t[3];
    if (!edge_math(vx, vy, vz, pair, sW2, g, t)) return;
    float* op = out + (size_t)c * 9;
    #pragma unroll
    for (int m = 0; m < 3; m++)
        #pragma unroll
        for (int o = 0; o < 3; o++)
            atomicAdd(op + m * 3 + o, g[m] * t[o]);
}

extern "C" void kernel_launch(void* const* d_in, const int* in_sizes, int n_in,
                              void* d_out, int out_size, void* d_ws, size_t ws_size,
                              hipStream_t stream) {
    const float* vecs      = (const float*)d_in[0];
    const int*   centers   = (const int*)d_in[1];
    const int*   neighbors = (const int*)d_in[2];
    const int*   species   = (const int*)d_in[3];
    const float* W_alch    = (const float*)d_in[6];
    const float* cemb      = (const float*)d_in[7];
    const float* Wc        = (const float*)d_in[8];
    float*       out       = (float*)d_out;

    int E = in_sizes[1];
    int A = in_sizes[3];
    int nbin    = (A + APB - 1) >> APB_SH;
    int nblocks = (E + PH1_REC - 1) / PH1_REC;

    // ws: [gcnt nbin u32 | pad 256B] [payload nbin*BSTR int4]
    size_t gc_bytes = ((size_t)nbin * 4 + 255) & ~(size_t)255;
    size_t need = gc_bytes + (size_t)nbin * BSTR * 16;

    if (nbin <= NBIN_PAD && need <= ws_size) {
        unsigned* gcnt = (unsigned*)d_ws;
        int4* payload = (int4*)((char*)d_ws + gc_bytes);

        hipMemsetAsync(gcnt, 0, (size_t)nbin * 4, stream);
        vb_phase1<<<nblocks, PH1_BLK, 0, stream>>>(vecs, centers, neighbors,
                                                   species, W_alch, cemb, Wc,
                                                   gcnt, payload, E, nbin);
        vb_phase2<<<nbin, 256, 0, stream>>>(gcnt, payload, out, A);
    } else {
        hipMemsetAsync(d_out, 0, (size_t)out_size * sizeof(float), stream);
        int grid = (E + 255) / 256;
        vb_edge_fallback<<<grid, 256, 0, stream>>>(vecs, centers, neighbors,
                                                   species, W_alch, cemb, Wc,
                                                   out, E);
    }
}

// Round 4
// 157.793 us; speedup vs baseline: 1.4130x; 1.4130x over previous
//
#include <hip/hip_runtime.h>
#include <hip/hip_fp16.h>

// VectorBasis R16. Base = R14 phase1 (proven, untouched: block-major sorted
// chunks + u16 runoff table, fully coalesced dump, 4 blocks/CU). Phase2
// rebuilt after R15's lesson (f32 LDS atomics ~200cyc each -> 97us; int LDS
// atomics fast): direct-sorted-scatter owner-compute:
//  - gather records into REGISTERS (static rec[7], launch_bounds(256,4)),
//    histogram by atom via packed-u16 int LDS atomics (rank = returned old),
//  - after the 128-key scan, write each record DIRECTLY to its sorted slot
//    aexcl[key]+rank (no sidx array at all),
//  - owner accumulate reads a CONTIGUOUS srec2 run (ds_read_b128 stream)
//    instead of the old indirect dependent ds_read_u16 -> ds_read_b128 chain.
//  - CAP2 1536->1792 (LDS 37.1KB, still 4 blocks/CU = 1024 >= 782 resident,
//    no straggler round), chunk2 shrinks to ~256 records.
// Per record this deletes 2 LDS ops and a dependent-latency chain; per chunk
// it deletes the sidx scatter pass. ~90us of harness ws-poison fills bound
// the wall from below.

constexpr int NSP  = 4;
constexpr int NRAD = 8;
constexpr int NPS  = 4;
constexpr int DDIM = NRAD * NPS;       // 32

constexpr int APB       = 128;         // atoms per bin
constexpr int APB_SH    = 7;
constexpr int NBIN_PAD  = 832;         // 64*13 >= nbin(782)
constexpr int NROWS_PAD = 832;         // >= nblocks(782)
constexpr int RS        = 840;         // runoff row stride (u16), >= nbin+1
constexpr int PH1_BLK   = 512;
constexpr int PH1_U     = 4;
constexpr int PH1_REC   = PH1_BLK * PH1_U;  // 2048
constexpr int CAP2      = 1792;        // phase2 LDS chunk (records), 7*256
constexpr int IT2       = CAP2 / 256;  // 7 (static)

__device__ __forceinline__ unsigned pack2(float a, float b) {
    union { __half2 h; unsigned u; } cv;
    cv.h = __floats2half2_rn(a, b);
    return cv.u;
}
__device__ __forceinline__ float2 unpack2(unsigned u) {
    union { unsigned u; __half2 h; } cv;
    cv.u = u;
    return __half22float2(cv.h);
}

__device__ __forceinline__ void build_w2(
    float* sW2, const float* cemb, const float* Wc, const float* W_alch,
    int tid, int nthreads)
{
    for (int i = tid; i < 3 * NRAD * 16; i += nthreads) {
        int p  = i & 15;
        int n  = (i >> 4) & 7;
        int o  = i >> 7;
        int sc = p >> 2, sn = p & 3;
        float w = 0.0f;
        #pragma unroll
        for (int q = 0; q < NPS; q++)
            w += cemb[sc * DDIM + n * NPS + q] * Wc[o * DDIM + n * NPS + q]
               * W_alch[sn * NPS + q];
        sW2[i] = w;
    }
}

__device__ __forceinline__ bool edge_math(
    float vx, float vy, float vz, int pair, const float* sW2,
    float g[3], float t[3])
{
    float d2    = vx * vx + vy * vy + vz * vz + 1e-12f;
    float d     = sqrtf(d2);
    float inv_d = 1.0f / d;

    const float PI = 3.14159265358979323846f;
    const float RCUT = 5.0f, INNER = 4.5f, INVW = 2.0f;
    if (d >= RCUT) return false;
    float taper = 0.5f * (__cosf(PI * (d - INNER) * INVW) + 1.0f);
    float fc = (d < INNER) ? 1.0f : taper;

    float theta = (PI / RCUT) * d;
    float s1 = __sinf(theta);
    float c1 = __cosf(theta);
    float two_c = 2.0f * c1;
    float R[NRAD];
    R[0] = s1 * inv_d;
    float sm2 = 0.0f, sm1 = s1;
    #pragma unroll
    for (int n = 1; n < NRAD; n++) {
        float s = two_c * sm1 - sm2;
        sm2 = sm1; sm1 = s;
        R[n] = s * inv_d;
    }

    #pragma unroll
    for (int o = 0; o < 3; o++) {
        float acc = 0.0f;
        #pragma unroll
        for (int n = 0; n < NRAD; n++)
            acc += R[n] * sW2[(o * NRAD + n) * 16 + pair];
        t[o] = acc;
    }
    g[0] = fc * vy * inv_d;
    g[1] = fc * vz * inv_d;
    g[2] = fc * vx * inv_d;
    return true;
}

// ====== phase1: block-private sorted chunk + offset table ===================
__global__ __launch_bounds__(PH1_BLK) void vb_phase1(
    const float* __restrict__ vecs,
    const int*   __restrict__ centers,
    const int*   __restrict__ neighbors,
    const int*   __restrict__ species,
    const float* __restrict__ W_alch,
    const float* __restrict__ cemb,
    const float* __restrict__ Wc,
    unsigned short* __restrict__ runoff,  // (nblocks, RS)
    int4*        __restrict__ payload,    // (nblocks, PH1_REC)
    int E, int nbin)
{
    __shared__ float sW2[3 * NRAD * 16];        // 1.5 KB
    __shared__ int4  srec[PH1_REC];             // 32 KB
    __shared__ unsigned lcntP[NBIN_PAD / 2];    // 1.66 KB packed u16 pairs
    __shared__ unsigned short lexcl[NBIN_PAD];  // 1.66 KB
    __shared__ int sTotal;

    int tid = threadIdx.x;
    build_w2(sW2, cemb, Wc, W_alch, tid, PH1_BLK);
    for (int i = tid; i < NBIN_PAD / 2; i += PH1_BLK) lcntP[i] = 0;
    __syncthreads();

    int4 rec[PH1_U];
    int  rnk[PH1_U];   // static indices only — stays in VGPRs
    #pragma unroll
    for (int u = 0; u < PH1_U; u++) {
        int e = blockIdx.x * PH1_REC + u * PH1_BLK + tid;
        rec[u].x = -1;
        rnk[u]   = 0;
        if (e < E) {
            float vx = vecs[3 * e + 0];
            float vy = vecs[3 * e + 1];
            float vz = vecs[3 * e + 2];
            int c  = centers[e];
            int pair = species[c] * 4 + species[neighbors[e]];
            float g[3], t[3];
            if (edge_math(vx, vy, vz, pair, sW2, g, t)) {
                rec[u].x = c;
                rec[u].y = (int)pack2(g[0], g[1]);
                rec[u].z = (int)pack2(g[2], t[0]);
                rec[u].w = (int)pack2(t[1], t[2]);
                int bin = c >> APB_SH;
                int sh  = (bin & 1) << 4;
                unsigned old = atomicAdd(&lcntP[bin >> 1], 1u << sh);
                rnk[u] = (int)((old >> sh) & 0xffff);   // arrival rank in bin
            }
        }
    }
    __syncthreads();

    // single-wave exclusive scan over NBIN_PAD bins (13/lane), packed counts
    if (tid < 64) {
        int base = tid * 13;
        int pre[13];
        int sum = 0;
        #pragma unroll
        for (int j = 0; j < 13; j++) {
            int b = base + j;
            int n = (lcntP[b >> 1] >> ((b & 1) << 4)) & 0xffff;
            pre[j] = sum; sum += n;
        }
        int incl = sum;
        #pragma unroll
        for (int off = 1; off < 64; off <<= 1) {
            int t = __shfl_up(incl, off, 64);
            if (tid >= off) incl += t;
        }
        int ex = incl - sum;
        #pragma unroll
        for (int j = 0; j < 13; j++)
            lexcl[base + j] = (unsigned short)(ex + pre[j]);
        if (tid == 63) sTotal = incl;
    }
    __syncthreads();

    // scatter records into LDS sorted by bin — NO atomic (slot = excl + rank)
    #pragma unroll
    for (int u = 0; u < PH1_U; u++) {
        if (rec[u].x >= 0) {
            int bin = rec[u].x >> APB_SH;
            srec[(int)lexcl[bin] + rnk[u]] = rec[u];
        }
    }
    __syncthreads();

    // fully coalesced chunk dump + offset table
    int total = sTotal;
    size_t pbase = (size_t)blockIdx.x * PH1_REC;
    for (int i = tid; i < total; i += PH1_BLK)
        payload[pbase + i] = srec[i];
    unsigned short* ro = runoff + (size_t)blockIdx.x * RS;
    for (int b = tid; b <= nbin; b += PH1_BLK)
        ro[b] = (b < nbin) ? lexcl[b] : (unsigned short)total;
}

// ====== phase2: bsearch gather -> rank -> direct sorted scatter =============
__global__ __launch_bounds__(256, 4) void vb_phase2(
    const unsigned short* __restrict__ runoff,   // (nblocks, RS)
    const int4*           __restrict__ payload,  // (nblocks, PH1_REC)
    float*                __restrict__ out,      // (A,9), fully overwritten
    int A, int nblocks)
{
    __shared__ int4 srec2[CAP2];                    // 28 KB
    __shared__ unsigned short sst[NROWS_PAD];       // 1.66 KB run start
    __shared__ unsigned short roff[NROWS_PAD];      // 1.66 KB excl scan
    __shared__ unsigned cntP[APB / 2];              // 256 B packed u16 counts
    __shared__ unsigned short aexcl[APB];           // 256 B
    __shared__ float sout[APB * 9];                 // 4.5 KB
    __shared__ int sTotal;                          // ~37.1 KB -> 4/CU

    int b   = blockIdx.x;
    int tid = threadIdx.x;

    // run table for this bin: start-in-chunk and length per source block
    for (int r = tid; r < NROWS_PAD; r += 256) {
        unsigned short s0 = 0, len = 0;
        if (r < nblocks) {
            const unsigned short* row = runoff + (size_t)r * RS + b;
            s0  = row[0];
            len = (unsigned short)(row[1] - row[0]);
        }
        sst[r]  = s0;
        roff[r] = len;   // temporarily lengths; scanned in place below
    }
    __syncthreads();

    // single-wave exclusive scan over NROWS_PAD rows (13/lane)
    // rows >= nblocks have len 0, so roff[r>=nblocks] == total (sentinel-free:
    // nblocks(782) < NROWS_PAD(832) and bsearch touches roff[m<=nblocks])
    if (tid < 64) {
        int base = tid * 13;
        int pre[13];
        int sum = 0;
        #pragma unroll
        for (int j = 0; j < 13; j++) { pre[j] = sum; sum += roff[base + j]; }
        int incl = sum;
        #pragma unroll
        for (int off = 1; off < 64; off <<= 1) {
            int t = __shfl_up(incl, off, 64);
            if (tid >= off) incl += t;
        }
        int ex = incl - sum;
        #pragma unroll
        for (int j = 0; j < 13; j++)
            roff[base + j] = (unsigned short)(ex + pre[j]);
        if (tid == 63) sTotal = incl;
    }
    __syncthreads();

    int total = sTotal;
    float acc[9] = {0,0,0,0,0,0,0,0,0};
    int half = tid >> 7;          // 0: first half of records, 1: second half
    int atom = tid & (APB - 1);   // each atom owned by 2 threads

    for (int w0 = 0; w0 < total; w0 += CAP2) {
        int nc = min(CAP2, total - w0);

        if (tid < APB / 2) cntP[tid] = 0;
        __syncthreads();

        // gather (bsearch, coalesced) into REGISTERS + histogram-with-rank
        int4 rec[IT2];
        int  krnk[IT2];   // (rank<<8)|key, -1 = empty; static indices only
        #pragma unroll
        for (int it = 0; it < IT2; it++) {
            int i = it * 256 + tid;
            krnk[it] = -1;
            if (i < nc) {
                int p = w0 + i;
                int l = 0, h = nblocks;   // roff[l] <= p < roff[h]
                #pragma unroll 1
                while (h - l > 1) {
                    int m = (l + h) >> 1;
                    if ((int)roff[m] <= p) l = m; else h = m;
                }
                int j = p - (int)roff[l];
                rec[it] = payload[(size_t)l * PH1_REC + (int)sst[l] + j];
                int k = rec[it].x & (APB - 1);
                int sh = (k & 1) << 4;
                unsigned old = atomicAdd(&cntP[k >> 1], 1u << sh);
                int rnk = (int)((old >> sh) & 0xffff);
                krnk[it] = (rnk << 8) | k;
            }
        }
        __syncthreads();

        // single-wave exclusive scan over 128 keys (packed pair per lane)
        if (tid < 64) {
            unsigned cp = cntP[tid];
            int c0 = (int)(cp & 0xffff), c1 = (int)(cp >> 16);
            int s1 = c0 + c1;
            int incl = s1;
            #pragma unroll
            for (int off = 1; off < 64; off <<= 1) {
                int t = __shfl_up(incl, off, 64);
                if (tid >= off) incl += t;
            }
            int ex = incl - s1;
            aexcl[2 * tid]     = (unsigned short)ex;
            aexcl[2 * tid + 1] = (unsigned short)(ex + c0);
        }
        __syncthreads();

        // direct sorted scatter: record -> slot aexcl[key]+rank (no sidx)
        #pragma unroll
        for (int it = 0; it < IT2; it++) {
            if (krnk[it] >= 0) {
                int k = krnk[it] & (APB - 1);
                srec2[(int)aexcl[k] + (krnk[it] >> 8)] = rec[it];
            }
        }
        __syncthreads();

        // accumulation: 2 threads per atom, contiguous b128 stream
        {
            int st = (int)aexcl[atom];
            unsigned cp = cntP[atom >> 1];
            int n = (int)((cp >> ((atom & 1) << 4)) & 0xffff);
            int mid = st + ((n + 1) >> 1);
            int lo = half ? mid : st;
            int hi = half ? (st + n) : mid;
            for (int j = lo; j < hi; j++) {
                int4 r = srec2[j];
                float2 g01 = unpack2((unsigned)r.y);
                float2 g2t = unpack2((unsigned)r.z);
                float2 t12 = unpack2((unsigned)r.w);
                float g0 = g01.x, g1 = g01.y, g2 = g2t.x;
                float t0 = g2t.y, t1 = t12.x, t2 = t12.y;
                acc[0] += g0 * t0; acc[1] += g0 * t1; acc[2] += g0 * t2;
                acc[3] += g1 * t0; acc[4] += g1 * t1; acc[5] += g1 * t2;
                acc[6] += g2 * t0; acc[7] += g2 * t1; acc[8] += g2 * t2;
            }
        }
        __syncthreads();   // srec2/cntP reused next chunk
    }

    // combine the two halves and overwrite out (coalesced)
    if (half == 0) {
        #pragma unroll
        for (int k = 0; k < 9; k++) sout[atom * 9 + k] = acc[k];
    }
    __syncthreads();
    if (half == 1) {
        #pragma unroll
        for (int k = 0; k < 9; k++) sout[atom * 9 + k] += acc[k];
    }
    __syncthreads();
    size_t gbase = (size_t)b * APB * 9;
    size_t lim = (size_t)A * 9;
    for (int i = tid; i < APB * 9; i += 256) {
        size_t gi = gbase + i;
        if (gi < lim) out[gi] = sout[i];
    }
}

// Fallback: direct per-edge global atomics (correct, slow).
__global__ __launch_bounds__(256) void vb_edge_fallback(
    const float* __restrict__ vecs,
    const int*   __restrict__ centers,
    const int*   __restrict__ neighbors,
    const int*   __restrict__ species,
    const float* __restrict__ W_alch,
    const float* __restrict__ cemb,
    const float* __restrict__ Wc,
    float*       __restrict__ out,
    int E)
{
    __shared__ float sW2[3 * NRAD * 16];
    build_w2(sW2, cemb, Wc, W_alch, threadIdx.x, blockDim.x);
    __syncthreads();

    int e = blockIdx.x * blockDim.x + threadIdx.x;
    if (e >= E) return;
    float vx = vecs[3 * e + 0], vy = vecs[3 * e + 1], vz = vecs[3 * e + 2];
    int c = centers[e];
    int pair = species[c] * 4 + species[neighbors[e]];
    float g[3], t[3];
    if (!edge_math(vx, vy, vz, pair, sW2, g, t)) return;
    float* op = out + (size_t)c * 9;
    #pragma unroll
    for (int m = 0; m < 3; m++)
        #pragma unroll
        for (int o = 0; o < 3; o++)
            atomicAdd(op + m * 3 + o, g[m] * t[o]);
}

extern "C" void kernel_launch(void* const* d_in, const int* in_sizes, int n_in,
                              void* d_out, int out_size, void* d_ws, size_t ws_size,
                              hipStream_t stream) {
    const float* vecs      = (const float*)d_in[0];
    const int*   centers   = (const int*)d_in[1];
    const int*   neighbors = (const int*)d_in[2];
    const int*   species   = (const int*)d_in[3];
    const float* W_alch    = (const float*)d_in[6];
    const float* cemb      = (const float*)d_in[7];
    const float* Wc        = (const float*)d_in[8];
    float*       out       = (float*)d_out;

    int E = in_sizes[1];
    int A = in_sizes[3];
    int nbin    = (A + APB - 1) >> APB_SH;
    int nblocks = (E + PH1_REC - 1) / PH1_REC;

    // ws: [runoff nblocks*RS u16][payload nblocks*2048*16B]
    size_t ro_bytes = ((size_t)nblocks * RS * 2 + 255) & ~(size_t)255;
    size_t need = ro_bytes + (size_t)nblocks * PH1_REC * 16;

    if (nbin + 1 <= RS && nbin <= NBIN_PAD && nblocks < NROWS_PAD &&
        need <= ws_size) {
        unsigned short* runoff = (unsigned short*)d_ws;
        int4* payload = (int4*)((char*)d_ws + ro_bytes);

        vb_phase1<<<nblocks, PH1_BLK, 0, stream>>>(vecs, centers, neighbors,
                                                   species, W_alch, cemb, Wc,
                                                   runoff, payload, E, nbin);
        vb_phase2<<<nbin, 256, 0, stream>>>(runoff, payload, out, A, nblocks);
    } else {
        hipMemsetAsync(d_out, 0, (size_t)out_size * sizeof(float), stream);
        int grid = (E + 255) / 256;
        vb_edge_fallback<<<grid, 256, 0, stream>>>(vecs, centers, neighbors,
                                                   species, W_alch, cemb, Wc,
                                                   out, E);
    }
}

// Round 5
// 126.431 us; speedup vs baseline: 1.7635x; 1.2481x over previous
//
#include <hip/hip_runtime.h>
#include <hip/hip_fp16.h>

// VectorBasis R17. Phase1 = R14 verbatim (proven: block-major sorted chunks
// + u16 runoff table, coalesced dump). Phase2 rebuilt around FIXED-POINT INT
// LDS accumulation, using three hard-won facts:
//   R15: f32 LDS atomicAdd ~200cyc (CAS) -> 97us. Unusable.
//   R12/R14: INT LDS atomics are fast (1.6M inside the ~12us phase1).
//   R16: register-held records across barriers -> scratch spill (+14MB
//        WRITE_SIZE, 53us). Records must stream, not persist.
// New phase2: run-table+scan (proven) -> rid window table (proven R14) ->
// stream payload (coalesced) -> unpack -> 9x atomicAdd(int) into a 4.5KB
// fixed-point tile (scale 2^-15) -> scaled write-out. Deletes histogram/
// rank/scan/scatter/sidx/srec2/owner-loop/half-merge and ~11 barriers.
// LDS 16KB -> all 782 blocks resident (8/CU), no straggler geometry, and
// int accumulation is order-independent (deterministic). Precision: |g.t|
// <~60, per-atom sums <~1e3 << 2^31/2^15; rn-quantization ~1.5e-5/record,
// accumulated ~4e-5 << fp16 record noise (absmax 2^-7 passes every round).
// ~90us of harness ws-poison fills bounds the wall from below.

constexpr int NSP  = 4;
constexpr int NRAD = 8;
constexpr int NPS  = 4;
constexpr int DDIM = NRAD * NPS;       // 32

constexpr int APB       = 128;         // atoms per bin
constexpr int APB_SH    = 7;
constexpr int NBIN_PAD  = 832;         // 64*13 >= nbin(782)
constexpr int NROWS_PAD = 832;         // >= nblocks(782)+1 (scan sentinel)
constexpr int RS        = 840;         // runoff row stride (u16), >= nbin+1
constexpr int PH1_BLK   = 512;
constexpr int PH1_U     = 4;
constexpr int PH1_REC   = PH1_BLK * PH1_U;  // 2048
constexpr int CAPR      = 4096;        // phase2 rid window (records)

constexpr float ACC_SCALE     = 32768.0f;        // 2^15 fixed point
constexpr float ACC_INV_SCALE = 1.0f / 32768.0f;

__device__ __forceinline__ unsigned pack2(float a, float b) {
    union { __half2 h; unsigned u; } cv;
    cv.h = __floats2half2_rn(a, b);
    return cv.u;
}
__device__ __forceinline__ float2 unpack2(unsigned u) {
    union { unsigned u; __half2 h; } cv;
    cv.u = u;
    return __half22float2(cv.h);
}

__device__ __forceinline__ void build_w2(
    float* sW2, const float* cemb, const float* Wc, const float* W_alch,
    int tid, int nthreads)
{
    for (int i = tid; i < 3 * NRAD * 16; i += nthreads) {
        int p  = i & 15;
        int n  = (i >> 4) & 7;
        int o  = i >> 7;
        int sc = p >> 2, sn = p & 3;
        float w = 0.0f;
        #pragma unroll
        for (int q = 0; q < NPS; q++)
            w += cemb[sc * DDIM + n * NPS + q] * Wc[o * DDIM + n * NPS + q]
               * W_alch[sn * NPS + q];
        sW2[i] = w;
    }
}

__device__ __forceinline__ bool edge_math(
    float vx, float vy, float vz, int pair, const float* sW2,
    float g[3], float t[3])
{
    float d2    = vx * vx + vy * vy + vz * vz + 1e-12f;
    float d     = sqrtf(d2);
    float inv_d = 1.0f / d;

    const float PI = 3.14159265358979323846f;
    const float RCUT = 5.0f, INNER = 4.5f, INVW = 2.0f;
    if (d >= RCUT) return false;
    float taper = 0.5f * (__cosf(PI * (d - INNER) * INVW) + 1.0f);
    float fc = (d < INNER) ? 1.0f : taper;

    float theta = (PI / RCUT) * d;
    float s1 = __sinf(theta);
    float c1 = __cosf(theta);
    float two_c = 2.0f * c1;
    float R[NRAD];
    R[0] = s1 * inv_d;
    float sm2 = 0.0f, sm1 = s1;
    #pragma unroll
    for (int n = 1; n < NRAD; n++) {
        float s = two_c * sm1 - sm2;
        sm2 = sm1; sm1 = s;
        R[n] = s * inv_d;
    }

    #pragma unroll
    for (int o = 0; o < 3; o++) {
        float acc = 0.0f;
        #pragma unroll
        for (int n = 0; n < NRAD; n++)
            acc += R[n] * sW2[(o * NRAD + n) * 16 + pair];
        t[o] = acc;
    }
    g[0] = fc * vy * inv_d;
    g[1] = fc * vz * inv_d;
    g[2] = fc * vx * inv_d;
    return true;
}

// ====== phase1: block-private sorted chunk + offset table ===================
__global__ __launch_bounds__(PH1_BLK) void vb_phase1(
    const float* __restrict__ vecs,
    const int*   __restrict__ centers,
    const int*   __restrict__ neighbors,
    const int*   __restrict__ species,
    const float* __restrict__ W_alch,
    const float* __restrict__ cemb,
    const float* __restrict__ Wc,
    unsigned short* __restrict__ runoff,  // (nblocks, RS)
    int4*        __restrict__ payload,    // (nblocks, PH1_REC)
    int E, int nbin)
{
    __shared__ float sW2[3 * NRAD * 16];        // 1.5 KB
    __shared__ int4  srec[PH1_REC];             // 32 KB
    __shared__ unsigned lcntP[NBIN_PAD / 2];    // 1.66 KB packed u16 pairs
    __shared__ unsigned short lexcl[NBIN_PAD];  // 1.66 KB
    __shared__ int sTotal;

    int tid = threadIdx.x;
    build_w2(sW2, cemb, Wc, W_alch, tid, PH1_BLK);
    for (int i = tid; i < NBIN_PAD / 2; i += PH1_BLK) lcntP[i] = 0;
    __syncthreads();

    int4 rec[PH1_U];
    int  rnk[PH1_U];   // static indices only — stays in VGPRs
    #pragma unroll
    for (int u = 0; u < PH1_U; u++) {
        int e = blockIdx.x * PH1_REC + u * PH1_BLK + tid;
        rec[u].x = -1;
        rnk[u]   = 0;
        if (e < E) {
            float vx = vecs[3 * e + 0];
            float vy = vecs[3 * e + 1];
            float vz = vecs[3 * e + 2];
            int c  = centers[e];
            int pair = species[c] * 4 + species[neighbors[e]];
            float g[3], t[3];
            if (edge_math(vx, vy, vz, pair, sW2, g, t)) {
                rec[u].x = c;
                rec[u].y = (int)pack2(g[0], g[1]);
                rec[u].z = (int)pack2(g[2], t[0]);
                rec[u].w = (int)pack2(t[1], t[2]);
                int bin = c >> APB_SH;
                int sh  = (bin & 1) << 4;
                unsigned old = atomicAdd(&lcntP[bin >> 1], 1u << sh);
                rnk[u] = (int)((old >> sh) & 0xffff);   // arrival rank in bin
            }
        }
    }
    __syncthreads();

    // single-wave exclusive scan over NBIN_PAD bins (13/lane), packed counts
    if (tid < 64) {
        int base = tid * 13;
        int pre[13];
        int sum = 0;
        #pragma unroll
        for (int j = 0; j < 13; j++) {
            int b = base + j;
            int n = (lcntP[b >> 1] >> ((b & 1) << 4)) & 0xffff;
            pre[j] = sum; sum += n;
        }
        int incl = sum;
        #pragma unroll
        for (int off = 1; off < 64; off <<= 1) {
            int t = __shfl_up(incl, off, 64);
            if (tid >= off) incl += t;
        }
        int ex = incl - sum;
        #pragma unroll
        for (int j = 0; j < 13; j++)
            lexcl[base + j] = (unsigned short)(ex + pre[j]);
        if (tid == 63) sTotal = incl;
    }
    __syncthreads();

    // scatter records into LDS sorted by bin — NO atomic (slot = excl + rank)
    #pragma unroll
    for (int u = 0; u < PH1_U; u++) {
        if (rec[u].x >= 0) {
            int bin = rec[u].x >> APB_SH;
            srec[(int)lexcl[bin] + rnk[u]] = rec[u];
        }
    }
    __syncthreads();

    // fully coalesced chunk dump + offset table
    int total = sTotal;
    size_t pbase = (size_t)blockIdx.x * PH1_REC;
    for (int i = tid; i < total; i += PH1_BLK)
        payload[pbase + i] = srec[i];
    unsigned short* ro = runoff + (size_t)blockIdx.x * RS;
    for (int b = tid; b <= nbin; b += PH1_BLK)
        ro[b] = (b < nbin) ? lexcl[b] : (unsigned short)total;
}

// ====== phase2: rid gather -> 9x int LDS atomics -> scaled writeout =========
__global__ __launch_bounds__(256) void vb_phase2(
    const unsigned short* __restrict__ runoff,   // (nblocks, RS)
    const int4*           __restrict__ payload,  // (nblocks, PH1_REC)
    float*                __restrict__ out,      // (A,9), fully overwritten
    int A, int nblocks)
{
    __shared__ unsigned short sst[NROWS_PAD];   // 1.66 KB run start in block
    __shared__ unsigned short roff[NROWS_PAD];  // 1.66 KB excl scan of lens
    __shared__ unsigned short rid[CAPR];        // 8 KB run id per position
    __shared__ int sacc[APB * 9];               // 4.5 KB fixed-point acc
    __shared__ int sTotal;                      // ~16 KB -> all blocks resident

    int b   = blockIdx.x;
    int tid = threadIdx.x;

    // run table for this bin: start-in-chunk and length per source block
    for (int r = tid; r < NROWS_PAD; r += 256) {
        unsigned short s0 = 0, len = 0;
        if (r < nblocks) {
            const unsigned short* row = runoff + (size_t)r * RS + b;
            s0  = row[0];
            len = (unsigned short)(row[1] - row[0]);
        }
        sst[r]  = s0;
        roff[r] = len;   // temporarily lengths; scanned in place below
    }
    for (int i = tid; i < APB * 9; i += 256) sacc[i] = 0;
    __syncthreads();

    // single-wave exclusive scan over NROWS_PAD rows (13/lane).
    // rows >= nblocks have len 0 so roff[nblocks] == total (sentinel,
    // in-range since nblocks < NROWS_PAD).
    if (tid < 64) {
        int base = tid * 13;
        int pre[13];
        int sum = 0;
        #pragma unroll
        for (int j = 0; j < 13; j++) { pre[j] = sum; sum += roff[base + j]; }
        int incl = sum;
        #pragma unroll
        for (int off = 1; off < 64; off <<= 1) {
            int t = __shfl_up(incl, off, 64);
            if (tid >= off) incl += t;
        }
        int ex = incl - sum;
        #pragma unroll
        for (int j = 0; j < 13; j++)
            roff[base + j] = (unsigned short)(ex + pre[j]);
        if (tid == 63) sTotal = incl;
    }
    __syncthreads();

    int total = sTotal;

    for (int w0 = 0; w0 < total; w0 += CAPR) {       // virtually always 1 pass
        int wend = min(w0 + CAPR, total);
        int nc = wend - w0;

        // rid for this window: disjoint clipped row ranges, no atomics
        for (int r = tid; r < nblocks; r += 256) {
            int s  = max((int)roff[r], w0);
            int e2 = min((int)roff[r + 1], wend);
            for (int p = s; p < e2; p++)
                rid[p - w0] = (unsigned short)r;
        }
        __syncthreads();

        // stream records (coalesced), accumulate via native int LDS atomics
        for (int i = tid; i < nc; i += 256) {
            int p = w0 + i;
            int l = (int)rid[i];
            int j = p - (int)roff[l];
            int4 r = payload[(size_t)l * PH1_REC + (int)sst[l] + j];
            int atom = r.x & (APB - 1);
            float2 g01 = unpack2((unsigned)r.y);
            float2 g2t = unpack2((unsigned)r.z);
            float2 t12 = unpack2((unsigned)r.w);
            float g0 = g01.x * ACC_SCALE, g1 = g01.y * ACC_SCALE;
            float g2 = g2t.x * ACC_SCALE;
            float t0 = g2t.y, t1 = t12.x, t2 = t12.y;
            int* s = &sacc[atom * 9];
            atomicAdd(s + 0, __float2int_rn(g0 * t0));
            atomicAdd(s + 1, __float2int_rn(g0 * t1));
            atomicAdd(s + 2, __float2int_rn(g0 * t2));
            atomicAdd(s + 3, __float2int_rn(g1 * t0));
            atomicAdd(s + 4, __float2int_rn(g1 * t1));
            atomicAdd(s + 5, __float2int_rn(g1 * t2));
            atomicAdd(s + 6, __float2int_rn(g2 * t0));
            atomicAdd(s + 7, __float2int_rn(g2 * t1));
            atomicAdd(s + 8, __float2int_rn(g2 * t2));
        }
        __syncthreads();   // rid reused next window (rare)
    }

    // scaled overwrite of out (coalesced)
    size_t gbase = (size_t)b * APB * 9;
    size_t lim = (size_t)A * 9;
    for (int i = tid; i < APB * 9; i += 256) {
        size_t gi = gbase + i;
        if (gi < lim) out[gi] = (float)sacc[i] * ACC_INV_SCALE;
    }
}

// Fallback: direct per-edge global atomics (correct, slow).
__global__ __launch_bounds__(256) void vb_edge_fallback(
    const float* __restrict__ vecs,
    const int*   __restrict__ centers,
    const int*   __restrict__ neighbors,
    const int*   __restrict__ species,
    const float* __restrict__ W_alch,
    const float* __restrict__ cemb,
    const float* __restrict__ Wc,
    float*       __restrict__ out,
    int E)
{
    __shared__ float sW2[3 * NRAD * 16];
    build_w2(sW2, cemb, Wc, W_alch, threadIdx.x, blockDim.x);
    __syncthreads();

    int e = blockIdx.x * blockDim.x + threadIdx.x;
    if (e >= E) return;
    float vx = vecs[3 * e + 0], vy = vecs[3 * e + 1], vz = vecs[3 * e + 2];
    int c = centers[e];
    int pair = species[c] * 4 + species[neighbors[e]];
    float g[3], t[3];
    if (!edge_math(vx, vy, vz, pair, sW2, g, t)) return;
    float* op = out + (size_t)c * 9;
    #pragma unroll
    for (int m = 0; m < 3; m++)
        #pragma unroll
        for (int o = 0; o < 3; o++)
            atomicAdd(op + m * 3 + o, g[m] * t[o]);
}

extern "C" void kernel_launch(void* const* d_in, const int* in_sizes, int n_in,
                              void* d_out, int out_size, void* d_ws, size_t ws_size,
                              hipStream_t stream) {
    const float* vecs      = (const float*)d_in[0];
    const int*   centers   = (const int*)d_in[1];
    const int*   neighbors = (const int*)d_in[2];
    const int*   species   = (const int*)d_in[3];
    const float* W_alch    = (const float*)d_in[6];
    const float* cemb      = (const float*)d_in[7];
    const float* Wc        = (const float*)d_in[8];
    float*       out       = (float*)d_out;

    int E = in_sizes[1];
    int A = in_sizes[3];
    int nbin    = (A + APB - 1) >> APB_SH;
    int nblocks = (E + PH1_REC - 1) / PH1_REC;

    // ws: [runoff nblocks*RS u16][payload nblocks*2048*16B]
    size_t ro_bytes = ((size_t)nblocks * RS * 2 + 255) & ~(size_t)255;
    size_t need = ro_bytes + (size_t)nblocks * PH1_REC * 16;

    if (nbin + 1 <= RS && nbin <= NBIN_PAD && nblocks < NROWS_PAD &&
        need <= ws_size) {
        unsigned short* runoff = (unsigned short*)d_ws;
        int4* payload = (int4*)((char*)d_ws + ro_bytes);

        vb_phase1<<<nblocks, PH1_BLK, 0, stream>>>(vecs, centers, neighbors,
                                                   species, W_alch, cemb, Wc,
                                                   runoff, payload, E, nbin);
        vb_phase2<<<nbin, 256, 0, stream>>>(runoff, payload, out, A, nblocks);
    } else {
        hipMemsetAsync(d_out, 0, (size_t)out_size * sizeof(float), stream);
        int grid = (E + 255) / 256;
        vb_edge_fallback<<<grid, 256, 0, stream>>>(vecs, centers, neighbors,
                                                   species, W_alch, cemb, Wc,
                                                   out, E);
    }
}

// Round 6
// 122.947 us; speedup vs baseline: 1.8135x; 1.0283x over previous
//
#include <hip/hip_runtime.h>
#include <hip/hip_fp16.h>

// VectorBasis R18. R17 (126.4us, best) + ONE change: XCD-affinity swizzle of
// phase2's bin index (T1, bijective m204 variant). Mechanism: payload is
// block-major; each bin reads 782 runs of ~42B, and a 128B line at a run
// boundary holds records of ~3 ADJACENT bins. Default dispatch puts adjacent
// bins on different XCDs (round-robin), so each shared line is fetched into
// ~3 per-XCD L2s -> R16 measured FETCH 55.7MB for a 25.6MB payload (2.2x).
// Grouping ~98 consecutive bins per XCD makes the shared-line neighbor hit
// the same L2. No data-layout change, no new risk.
// Proven structure unchanged: phase1 = block-major sorted chunks + u16
// runoff (R14); phase2 = rid gather + fixed-point INT LDS atomics (R17;
// f32 LDS atomics are ~200cyc CAS per R15, registers-across-barriers spill
// per R16). ~90us of harness ws-poison fills bounds the wall from below.

constexpr int NSP  = 4;
constexpr int NRAD = 8;
constexpr int NPS  = 4;
constexpr int DDIM = NRAD * NPS;       // 32

constexpr int APB       = 128;         // atoms per bin
constexpr int APB_SH    = 7;
constexpr int NBIN_PAD  = 832;         // 64*13 >= nbin(782)
constexpr int NROWS_PAD = 832;         // >= nblocks(782)+1 (scan sentinel)
constexpr int RS        = 840;         // runoff row stride (u16), >= nbin+1
constexpr int PH1_BLK   = 512;
constexpr int PH1_U     = 4;
constexpr int PH1_REC   = PH1_BLK * PH1_U;  // 2048
constexpr int CAPR      = 4096;        // phase2 rid window (records)
constexpr int NXCD      = 8;

constexpr float ACC_SCALE     = 32768.0f;        // 2^15 fixed point
constexpr float ACC_INV_SCALE = 1.0f / 32768.0f;

__device__ __forceinline__ unsigned pack2(float a, float b) {
    union { __half2 h; unsigned u; } cv;
    cv.h = __floats2half2_rn(a, b);
    return cv.u;
}
__device__ __forceinline__ float2 unpack2(unsigned u) {
    union { unsigned u; __half2 h; } cv;
    cv.u = u;
    return __half22float2(cv.h);
}

__device__ __forceinline__ void build_w2(
    float* sW2, const float* cemb, const float* Wc, const float* W_alch,
    int tid, int nthreads)
{
    for (int i = tid; i < 3 * NRAD * 16; i += nthreads) {
        int p  = i & 15;
        int n  = (i >> 4) & 7;
        int o  = i >> 7;
        int sc = p >> 2, sn = p & 3;
        float w = 0.0f;
        #pragma unroll
        for (int q = 0; q < NPS; q++)
            w += cemb[sc * DDIM + n * NPS + q] * Wc[o * DDIM + n * NPS + q]
               * W_alch[sn * NPS + q];
        sW2[i] = w;
    }
}

__device__ __forceinline__ bool edge_math(
    float vx, float vy, float vz, int pair, const float* sW2,
    float g[3], float t[3])
{
    float d2    = vx * vx + vy * vy + vz * vz + 1e-12f;
    float d     = sqrtf(d2);
    float inv_d = 1.0f / d;

    const float PI = 3.14159265358979323846f;
    const float RCUT = 5.0f, INNER = 4.5f, INVW = 2.0f;
    if (d >= RCUT) return false;
    float taper = 0.5f * (__cosf(PI * (d - INNER) * INVW) + 1.0f);
    float fc = (d < INNER) ? 1.0f : taper;

    float theta = (PI / RCUT) * d;
    float s1 = __sinf(theta);
    float c1 = __cosf(theta);
    float two_c = 2.0f * c1;
    float R[NRAD];
    R[0] = s1 * inv_d;
    float sm2 = 0.0f, sm1 = s1;
    #pragma unroll
    for (int n = 1; n < NRAD; n++) {
        float s = two_c * sm1 - sm2;
        sm2 = sm1; sm1 = s;
        R[n] = s * inv_d;
    }

    #pragma unroll
    for (int o = 0; o < 3; o++) {
        float acc = 0.0f;
        #pragma unroll
        for (int n = 0; n < NRAD; n++)
            acc += R[n] * sW2[(o * NRAD + n) * 16 + pair];
        t[o] = acc;
    }
    g[0] = fc * vy * inv_d;
    g[1] = fc * vz * inv_d;
    g[2] = fc * vx * inv_d;
    return true;
}

// ====== phase1: block-private sorted chunk + offset table ===================
__global__ __launch_bounds__(PH1_BLK) void vb_phase1(
    const float* __restrict__ vecs,
    const int*   __restrict__ centers,
    const int*   __restrict__ neighbors,
    const int*   __restrict__ species,
    const float* __restrict__ W_alch,
    const float* __restrict__ cemb,
    const float* __restrict__ Wc,
    unsigned short* __restrict__ runoff,  // (nblocks, RS)
    int4*        __restrict__ payload,    // (nblocks, PH1_REC)
    int E, int nbin)
{
    __shared__ float sW2[3 * NRAD * 16];        // 1.5 KB
    __shared__ int4  srec[PH1_REC];             // 32 KB
    __shared__ unsigned lcntP[NBIN_PAD / 2];    // 1.66 KB packed u16 pairs
    __shared__ unsigned short lexcl[NBIN_PAD];  // 1.66 KB
    __shared__ int sTotal;

    int tid = threadIdx.x;
    build_w2(sW2, cemb, Wc, W_alch, tid, PH1_BLK);
    for (int i = tid; i < NBIN_PAD / 2; i += PH1_BLK) lcntP[i] = 0;
    __syncthreads();

    int4 rec[PH1_U];
    int  rnk[PH1_U];   // static indices only — stays in VGPRs
    #pragma unroll
    for (int u = 0; u < PH1_U; u++) {
        int e = blockIdx.x * PH1_REC + u * PH1_BLK + tid;
        rec[u].x = -1;
        rnk[u]   = 0;
        if (e < E) {
            float vx = vecs[3 * e + 0];
            float vy = vecs[3 * e + 1];
            float vz = vecs[3 * e + 2];
            int c  = centers[e];
            int pair = species[c] * 4 + species[neighbors[e]];
            float g[3], t[3];
            if (edge_math(vx, vy, vz, pair, sW2, g, t)) {
                rec[u].x = c;
                rec[u].y = (int)pack2(g[0], g[1]);
                rec[u].z = (int)pack2(g[2], t[0]);
                rec[u].w = (int)pack2(t[1], t[2]);
                int bin = c >> APB_SH;
                int sh  = (bin & 1) << 4;
                unsigned old = atomicAdd(&lcntP[bin >> 1], 1u << sh);
                rnk[u] = (int)((old >> sh) & 0xffff);   // arrival rank in bin
            }
        }
    }
    __syncthreads();

    // single-wave exclusive scan over NBIN_PAD bins (13/lane), packed counts
    if (tid < 64) {
        int base = tid * 13;
        int pre[13];
        int sum = 0;
        #pragma unroll
        for (int j = 0; j < 13; j++) {
            int b = base + j;
            int n = (lcntP[b >> 1] >> ((b & 1) << 4)) & 0xffff;
            pre[j] = sum; sum += n;
        }
        int incl = sum;
        #pragma unroll
        for (int off = 1; off < 64; off <<= 1) {
            int t = __shfl_up(incl, off, 64);
            if (tid >= off) incl += t;
        }
        int ex = incl - sum;
        #pragma unroll
        for (int j = 0; j < 13; j++)
            lexcl[base + j] = (unsigned short)(ex + pre[j]);
        if (tid == 63) sTotal = incl;
    }
    __syncthreads();

    // scatter records into LDS sorted by bin — NO atomic (slot = excl + rank)
    #pragma unroll
    for (int u = 0; u < PH1_U; u++) {
        if (rec[u].x >= 0) {
            int bin = rec[u].x >> APB_SH;
            srec[(int)lexcl[bin] + rnk[u]] = rec[u];
        }
    }
    __syncthreads();

    // fully coalesced chunk dump + offset table
    int total = sTotal;
    size_t pbase = (size_t)blockIdx.x * PH1_REC;
    for (int i = tid; i < total; i += PH1_BLK)
        payload[pbase + i] = srec[i];
    unsigned short* ro = runoff + (size_t)blockIdx.x * RS;
    for (int b = tid; b <= nbin; b += PH1_BLK)
        ro[b] = (b < nbin) ? lexcl[b] : (unsigned short)total;
}

// ====== phase2: rid gather -> 9x int LDS atomics -> scaled writeout =========
__global__ __launch_bounds__(256) void vb_phase2(
    const unsigned short* __restrict__ runoff,   // (nblocks, RS)
    const int4*           __restrict__ payload,  // (nblocks, PH1_REC)
    float*                __restrict__ out,      // (A,9), fully overwritten
    int A, int nblocks)
{
    __shared__ unsigned short sst[NROWS_PAD];   // 1.66 KB run start in block
    __shared__ unsigned short roff[NROWS_PAD];  // 1.66 KB excl scan of lens
    __shared__ unsigned short rid[CAPR];        // 8 KB run id per position
    __shared__ int sacc[APB * 9];               // 4.5 KB fixed-point acc
    __shared__ int sTotal;                      // ~16 KB -> all blocks resident

    // XCD-affinity bin swizzle (T1, bijective m204 variant): group ~nbin/8
    // CONSECUTIVE bins per XCD so payload lines shared by adjacent bins'
    // runs are fetched into ONE per-XCD L2 instead of ~3.
    int nbin = gridDim.x;
    int q = nbin / NXCD, r0 = nbin % NXCD;
    int xcd = blockIdx.x % NXCD, loc = blockIdx.x / NXCD;
    int b = (xcd < r0 ? xcd * (q + 1) : r0 * (q + 1) + (xcd - r0) * q) + loc;

    int tid = threadIdx.x;

    // run table for this bin: start-in-chunk and length per source block
    for (int r = tid; r < NROWS_PAD; r += 256) {
        unsigned short s0 = 0, len = 0;
        if (r < nblocks) {
            const unsigned short* row = runoff + (size_t)r * RS + b;
            s0  = row[0];
            len = (unsigned short)(row[1] - row[0]);
        }
        sst[r]  = s0;
        roff[r] = len;   // temporarily lengths; scanned in place below
    }
    for (int i = tid; i < APB * 9; i += 256) sacc[i] = 0;
    __syncthreads();

    // single-wave exclusive scan over NROWS_PAD rows (13/lane).
    // rows >= nblocks have len 0 so roff[nblocks] == total (sentinel,
    // in-range since nblocks < NROWS_PAD).
    if (tid < 64) {
        int base = tid * 13;
        int pre[13];
        int sum = 0;
        #pragma unroll
        for (int j = 0; j < 13; j++) { pre[j] = sum; sum += roff[base + j]; }
        int incl = sum;
        #pragma unroll
        for (int off = 1; off < 64; off <<= 1) {
            int t = __shfl_up(incl, off, 64);
            if (tid >= off) incl += t;
        }
        int ex = incl - sum;
        #pragma unroll
        for (int j = 0; j < 13; j++)
            roff[base + j] = (unsigned short)(ex + pre[j]);
        if (tid == 63) sTotal = incl;
    }
    __syncthreads();

    int total = sTotal;

    for (int w0 = 0; w0 < total; w0 += CAPR) {       // virtually always 1 pass
        int wend = min(w0 + CAPR, total);
        int nc = wend - w0;

        // rid for this window: disjoint clipped row ranges, no atomics
        for (int r = tid; r < nblocks; r += 256) {
            int s  = max((int)roff[r], w0);
            int e2 = min((int)roff[r + 1], wend);
            for (int p = s; p < e2; p++)
                rid[p - w0] = (unsigned short)r;
        }
        __syncthreads();

        // stream records (coalesced), accumulate via native int LDS atomics
        for (int i = tid; i < nc; i += 256) {
            int p = w0 + i;
            int l = (int)rid[i];
            int j = p - (int)roff[l];
            int4 r = payload[(size_t)l * PH1_REC + (int)sst[l] + j];
            int atom = r.x & (APB - 1);
            float2 g01 = unpack2((unsigned)r.y);
            float2 g2t = unpack2((unsigned)r.z);
            float2 t12 = unpack2((unsigned)r.w);
            float g0 = g01.x * ACC_SCALE, g1 = g01.y * ACC_SCALE;
            float g2 = g2t.x * ACC_SCALE;
            float t0 = g2t.y, t1 = t12.x, t2 = t12.y;
            int* s = &sacc[atom * 9];
            atomicAdd(s + 0, __float2int_rn(g0 * t0));
            atomicAdd(s + 1, __float2int_rn(g0 * t1));
            atomicAdd(s + 2, __float2int_rn(g0 * t2));
            atomicAdd(s + 3, __float2int_rn(g1 * t0));
            atomicAdd(s + 4, __float2int_rn(g1 * t1));
            atomicAdd(s + 5, __float2int_rn(g1 * t2));
            atomicAdd(s + 6, __float2int_rn(g2 * t0));
            atomicAdd(s + 7, __float2int_rn(g2 * t1));
            atomicAdd(s + 8, __float2int_rn(g2 * t2));
        }
        __syncthreads();   // rid reused next window (rare)
    }

    // scaled overwrite of out (coalesced)
    size_t gbase = (size_t)b * APB * 9;
    size_t lim = (size_t)A * 9;
    for (int i = tid; i < APB * 9; i += 256) {
        size_t gi = gbase + i;
        if (gi < lim) out[gi] = (float)sacc[i] * ACC_INV_SCALE;
    }
}

// Fallback: direct per-edge global atomics (correct, slow).
__global__ __launch_bounds__(256) void vb_edge_fallback(
    const float* __restrict__ vecs,
    const int*   __restrict__ centers,
    const int*   __restrict__ neighbors,
    const int*   __restrict__ species,
    const float* __restrict__ W_alch,
    const float* __restrict__ cemb,
    const float* __restrict__ Wc,
    float*       __restrict__ out,
    int E)
{
    __shared__ float sW2[3 * NRAD * 16];
    build_w2(sW2, cemb, Wc, W_alch, threadIdx.x, blockDim.x);
    __syncthreads();

    int e = blockIdx.x * blockDim.x + threadIdx.x;
    if (e >= E) return;
    float vx = vecs[3 * e + 0], vy = vecs[3 * e + 1], vz = vecs[3 * e + 2];
    int c = centers[e];
    int pair = species[c] * 4 + species[neighbors[e]];
    float g[3], t[3];
    if (!edge_math(vx, vy, vz, pair, sW2, g, t)) return;
    float* op = out + (size_t)c * 9;
    #pragma unroll
    for (int m = 0; m < 3; m++)
        #pragma unroll
        for (int o = 0; o < 3; o++)
            atomicAdd(op + m * 3 + o, g[m] * t[o]);
}

extern "C" void kernel_launch(void* const* d_in, const int* in_sizes, int n_in,
                              void* d_out, int out_size, void* d_ws, size_t ws_size,
                              hipStream_t stream) {
    const float* vecs      = (const float*)d_in[0];
    const int*   centers   = (const int*)d_in[1];
    const int*   neighbors = (const int*)d_in[2];
    const int*   species   = (const int*)d_in[3];
    const float* W_alch    = (const float*)d_in[6];
    const float* cemb      = (const float*)d_in[7];
    const float* Wc        = (const float*)d_in[8];
    float*       out       = (float*)d_out;

    int E = in_sizes[1];
    int A = in_sizes[3];
    int nbin    = (A + APB - 1) >> APB_SH;
    int nblocks = (E + PH1_REC - 1) / PH1_REC;

    // ws: [runoff nblocks*RS u16][payload nblocks*2048*16B]
    size_t ro_bytes = ((size_t)nblocks * RS * 2 + 255) & ~(size_t)255;
    size_t need = ro_bytes + (size_t)nblocks * PH1_REC * 16;

    if (nbin + 1 <= RS && nbin <= NBIN_PAD && nblocks < NROWS_PAD &&
        need <= ws_size) {
        unsigned short* runoff = (unsigned short*)d_ws;
        int4* payload = (int4*)((char*)d_ws + ro_bytes);

        vb_phase1<<<nblocks, PH1_BLK, 0, stream>>>(vecs, centers, neighbors,
                                                   species, W_alch, cemb, Wc,
                                                   runoff, payload, E, nbin);
        vb_phase2<<<nbin, 256, 0, stream>>>(runoff, payload, out, A, nblocks);
    } else {
        hipMemsetAsync(d_out, 0, (size_t)out_size * sizeof(float), stream);
        int grid = (E + 255) / 256;
        vb_edge_fallback<<<grid, 256, 0, stream>>>(vecs, centers, neighbors,
                                                   species, W_alch, cemb, Wc,
                                                   out, E);
    }
}

// Round 7
// 118.315 us; speedup vs baseline: 1.8845x; 1.0391x over previous
//
#include <hip/hip_runtime.h>
#include <hip/hip_fp16.h>

// VectorBasis R19. R18 (122.9us best) + two fragmentation/latency changes:
//  1) PH1_BLK 512->1024, PH1_REC 2048->4096 (nblocks 782->391): payload runs
//     double to ~5.2 rec = 84B, cutting the 128B-line waste that R16 measured
//     as 2.2x fetch inflation (same mechanism the R18 swizzle attacked from
//     the dispatch side). Phase1 LDS 70KB -> 2 blocks/CU x 16 waves = 32
//     waves/CU (unchanged occupancy); all u16 ranges still safe.
//  2) phase2: 512 threads + u32 ADDRESS-BASE window table: sweep writes
//     abase[p-w0] = l*PH1_REC + sst[l] - roff[l], so the hot gather is
//     payload[w0+i+abase[i]] -- one ds_read_b32 instead of the dependent
//     rid->roff/sst chain; per-thread sequential record count halves.
// Frozen, proven: int fixed-point LDS accumulate (R17: f32 LDS atomics are
// ~200cyc CAS; R15), T1 XCD bin swizzle (R18: -3.5us), block-major coalesced
// dump (R14), no records held in regs across barriers (R16 spill lesson).
// ~90us of harness ws-poison fills bounds the wall from below.

constexpr int NSP  = 4;
constexpr int NRAD = 8;
constexpr int NPS  = 4;
constexpr int DDIM = NRAD * NPS;       // 32

constexpr int APB       = 128;         // atoms per bin
constexpr int APB_SH    = 7;
constexpr int NBIN_PAD  = 832;         // 64*13 >= nbin(782)
constexpr int NROWS_PAD = 832;         // >= nblocks(391)+1 (scan sentinel)
constexpr int RS        = 840;         // runoff row stride (u16), >= nbin+1
constexpr int PH1_BLK   = 1024;
constexpr int PH1_U     = 4;
constexpr int PH1_REC   = PH1_BLK * PH1_U;  // 4096
constexpr int CAPR      = 4096;        // phase2 window (records)
constexpr int P2_BLK    = 512;
constexpr int NXCD      = 8;

constexpr float ACC_SCALE     = 32768.0f;        // 2^15 fixed point
constexpr float ACC_INV_SCALE = 1.0f / 32768.0f;

__device__ __forceinline__ unsigned pack2(float a, float b) {
    union { __half2 h; unsigned u; } cv;
    cv.h = __floats2half2_rn(a, b);
    return cv.u;
}
__device__ __forceinline__ float2 unpack2(unsigned u) {
    union { unsigned u; __half2 h; } cv;
    cv.u = u;
    return __half22float2(cv.h);
}

__device__ __forceinline__ void build_w2(
    float* sW2, const float* cemb, const float* Wc, const float* W_alch,
    int tid, int nthreads)
{
    for (int i = tid; i < 3 * NRAD * 16; i += nthreads) {
        int p  = i & 15;
        int n  = (i >> 4) & 7;
        int o  = i >> 7;
        int sc = p >> 2, sn = p & 3;
        float w = 0.0f;
        #pragma unroll
        for (int q = 0; q < NPS; q++)
            w += cemb[sc * DDIM + n * NPS + q] * Wc[o * DDIM + n * NPS + q]
               * W_alch[sn * NPS + q];
        sW2[i] = w;
    }
}

__device__ __forceinline__ bool edge_math(
    float vx, float vy, float vz, int pair, const float* sW2,
    float g[3], float t[3])
{
    float d2    = vx * vx + vy * vy + vz * vz + 1e-12f;
    float d     = sqrtf(d2);
    float inv_d = 1.0f / d;

    const float PI = 3.14159265358979323846f;
    const float RCUT = 5.0f, INNER = 4.5f, INVW = 2.0f;
    if (d >= RCUT) return false;
    float taper = 0.5f * (__cosf(PI * (d - INNER) * INVW) + 1.0f);
    float fc = (d < INNER) ? 1.0f : taper;

    float theta = (PI / RCUT) * d;
    float s1 = __sinf(theta);
    float c1 = __cosf(theta);
    float two_c = 2.0f * c1;
    float R[NRAD];
    R[0] = s1 * inv_d;
    float sm2 = 0.0f, sm1 = s1;
    #pragma unroll
    for (int n = 1; n < NRAD; n++) {
        float s = two_c * sm1 - sm2;
        sm2 = sm1; sm1 = s;
        R[n] = s * inv_d;
    }

    #pragma unroll
    for (int o = 0; o < 3; o++) {
        float acc = 0.0f;
        #pragma unroll
        for (int n = 0; n < NRAD; n++)
            acc += R[n] * sW2[(o * NRAD + n) * 16 + pair];
        t[o] = acc;
    }
    g[0] = fc * vy * inv_d;
    g[1] = fc * vz * inv_d;
    g[2] = fc * vx * inv_d;
    return true;
}

// ====== phase1: block-private sorted chunk + offset table ===================
__global__ __launch_bounds__(PH1_BLK) void vb_phase1(
    const float* __restrict__ vecs,
    const int*   __restrict__ centers,
    const int*   __restrict__ neighbors,
    const int*   __restrict__ species,
    const float* __restrict__ W_alch,
    const float* __restrict__ cemb,
    const float* __restrict__ Wc,
    unsigned short* __restrict__ runoff,  // (nblocks, RS)
    int4*        __restrict__ payload,    // (nblocks, PH1_REC)
    int E, int nbin)
{
    __shared__ float sW2[3 * NRAD * 16];        // 1.5 KB
    __shared__ int4  srec[PH1_REC];             // 64 KB
    __shared__ unsigned lcntP[NBIN_PAD / 2];    // 1.66 KB packed u16 pairs
    __shared__ unsigned short lexcl[NBIN_PAD];  // 1.66 KB
    __shared__ int sTotal;                      // ~70 KB -> 2 blocks/CU

    int tid = threadIdx.x;
    build_w2(sW2, cemb, Wc, W_alch, tid, PH1_BLK);
    for (int i = tid; i < NBIN_PAD / 2; i += PH1_BLK) lcntP[i] = 0;
    __syncthreads();

    int4 rec[PH1_U];
    int  rnk[PH1_U];   // static indices only — stays in VGPRs
    #pragma unroll
    for (int u = 0; u < PH1_U; u++) {
        int e = blockIdx.x * PH1_REC + u * PH1_BLK + tid;
        rec[u].x = -1;
        rnk[u]   = 0;
        if (e < E) {
            float vx = vecs[3 * e + 0];
            float vy = vecs[3 * e + 1];
            float vz = vecs[3 * e + 2];
            int c  = centers[e];
            int pair = species[c] * 4 + species[neighbors[e]];
            float g[3], t[3];
            if (edge_math(vx, vy, vz, pair, sW2, g, t)) {
                rec[u].x = c;
                rec[u].y = (int)pack2(g[0], g[1]);
                rec[u].z = (int)pack2(g[2], t[0]);
                rec[u].w = (int)pack2(t[1], t[2]);
                int bin = c >> APB_SH;
                int sh  = (bin & 1) << 4;
                unsigned old = atomicAdd(&lcntP[bin >> 1], 1u << sh);
                rnk[u] = (int)((old >> sh) & 0xffff);   // arrival rank in bin
            }
        }
    }
    __syncthreads();

    // single-wave exclusive scan over NBIN_PAD bins (13/lane), packed counts
    if (tid < 64) {
        int base = tid * 13;
        int pre[13];
        int sum = 0;
        #pragma unroll
        for (int j = 0; j < 13; j++) {
            int b = base + j;
            int n = (lcntP[b >> 1] >> ((b & 1) << 4)) & 0xffff;
            pre[j] = sum; sum += n;
        }
        int incl = sum;
        #pragma unroll
        for (int off = 1; off < 64; off <<= 1) {
            int t = __shfl_up(incl, off, 64);
            if (tid >= off) incl += t;
        }
        int ex = incl - sum;
        #pragma unroll
        for (int j = 0; j < 13; j++)
            lexcl[base + j] = (unsigned short)(ex + pre[j]);
        if (tid == 63) sTotal = incl;
    }
    __syncthreads();

    // scatter records into LDS sorted by bin — NO atomic (slot = excl + rank)
    #pragma unroll
    for (int u = 0; u < PH1_U; u++) {
        if (rec[u].x >= 0) {
            int bin = rec[u].x >> APB_SH;
            srec[(int)lexcl[bin] + rnk[u]] = rec[u];
        }
    }
    __syncthreads();

    // fully coalesced chunk dump + offset table
    int total = sTotal;
    size_t pbase = (size_t)blockIdx.x * PH1_REC;
    for (int i = tid; i < total; i += PH1_BLK)
        payload[pbase + i] = srec[i];
    unsigned short* ro = runoff + (size_t)blockIdx.x * RS;
    for (int b = tid; b <= nbin; b += PH1_BLK)
        ro[b] = (b < nbin) ? lexcl[b] : (unsigned short)total;
}

// ====== phase2: abase gather -> 9x int LDS atomics -> scaled writeout =======
__global__ __launch_bounds__(P2_BLK) void vb_phase2(
    const unsigned short* __restrict__ runoff,   // (nblocks, RS)
    const int4*           __restrict__ payload,  // (nblocks, PH1_REC)
    float*                __restrict__ out,      // (A,9), fully overwritten
    int A, int nblocks)
{
    __shared__ unsigned short sst[NROWS_PAD];   // 1.66 KB run start in block
    __shared__ unsigned short roff[NROWS_PAD];  // 1.66 KB excl scan of lens
    __shared__ int   abase[CAPR];               // 16 KB addr base per position
    __shared__ int   sacc[APB * 9];             // 4.5 KB fixed-point acc
    __shared__ int sTotal;                      // ~24 KB -> 4 blocks/CU

    // XCD-affinity bin swizzle (T1, bijective): group ~nbin/8 CONSECUTIVE
    // bins per XCD so payload lines shared by adjacent bins' runs are
    // fetched into ONE per-XCD L2 instead of ~3.  (R18: -3.5us)
    int nbin = gridDim.x;
    int q = nbin / NXCD, r0 = nbin % NXCD;
    int xcd = blockIdx.x % NXCD, loc = blockIdx.x / NXCD;
    int b = (xcd < r0 ? xcd * (q + 1) : r0 * (q + 1) + (xcd - r0) * q) + loc;

    int tid = threadIdx.x;

    // run table for this bin: start-in-chunk and length per source block
    for (int r = tid; r < NROWS_PAD; r += P2_BLK) {
        unsigned short s0 = 0, len = 0;
        if (r < nblocks) {
            const unsigned short* row = runoff + (size_t)r * RS + b;
            s0  = row[0];
            len = (unsigned short)(row[1] - row[0]);
        }
        sst[r]  = s0;
        roff[r] = len;   // temporarily lengths; scanned in place below
    }
    for (int i = tid; i < APB * 9; i += P2_BLK) sacc[i] = 0;
    __syncthreads();

    // single-wave exclusive scan over NROWS_PAD rows (13/lane).
    // rows >= nblocks have len 0 so roff[nblocks] == total (sentinel,
    // in-range since nblocks < NROWS_PAD).
    if (tid < 64) {
        int base = tid * 13;
        int pre[13];
        int sum = 0;
        #pragma unroll
        for (int j = 0; j < 13; j++) { pre[j] = sum; sum += roff[base + j]; }
        int incl = sum;
        #pragma unroll
        for (int off = 1; off < 64; off <<= 1) {
            int t = __shfl_up(incl, off, 64);
            if (tid >= off) incl += t;
        }
        int ex = incl - sum;
        #pragma unroll
        for (int j = 0; j < 13; j++)
            roff[base + j] = (unsigned short)(ex + pre[j]);
        if (tid == 63) sTotal = incl;
    }
    __syncthreads();

    int total = sTotal;

    for (int w0 = 0; w0 < total; w0 += CAPR) {       // virtually always 1 pass
        int wend = min(w0 + CAPR, total);
        int nc = wend - w0;

        // abase for this window: disjoint clipped row ranges, no atomics.
        // abase[p-w0] = r*PH1_REC + sst[r] - roff[r]  =>  payload index of
        // global position p is simply p + abase[p-w0].
        for (int r = tid; r < nblocks; r += P2_BLK) {
            int s  = max((int)roff[r], w0);
            int e2 = min((int)roff[r + 1], wend);
            int base_r = r * PH1_REC + (int)sst[r] - (int)roff[r];
            for (int p = s; p < e2; p++)
                abase[p - w0] = base_r;
        }
        __syncthreads();

        // stream records (coalesced), accumulate via native int LDS atomics
        for (int i = tid; i < nc; i += P2_BLK) {
            int4 r = payload[(size_t)(w0 + i + abase[i])];
            int atom = r.x & (APB - 1);
            float2 g01 = unpack2((unsigned)r.y);
            float2 g2t = unpack2((unsigned)r.z);
            float2 t12 = unpack2((unsigned)r.w);
            float g0 = g01.x * ACC_SCALE, g1 = g01.y * ACC_SCALE;
            float g2 = g2t.x * ACC_SCALE;
            float t0 = g2t.y, t1 = t12.x, t2 = t12.y;
            int* s = &sacc[atom * 9];
            atomicAdd(s + 0, __float2int_rn(g0 * t0));
            atomicAdd(s + 1, __float2int_rn(g0 * t1));
            atomicAdd(s + 2, __float2int_rn(g0 * t2));
            atomicAdd(s + 3, __float2int_rn(g1 * t0));
            atomicAdd(s + 4, __float2int_rn(g1 * t1));
            atomicAdd(s + 5, __float2int_rn(g1 * t2));
            atomicAdd(s + 6, __float2int_rn(g2 * t0));
            atomicAdd(s + 7, __float2int_rn(g2 * t1));
            atomicAdd(s + 8, __float2int_rn(g2 * t2));
        }
        __syncthreads();   // abase reused next window (rare)
    }

    // scaled overwrite of out (coalesced)
    size_t gbase = (size_t)b * APB * 9;
    size_t lim = (size_t)A * 9;
    for (int i = tid; i < APB * 9; i += P2_BLK) {
        size_t gi = gbase + i;
        if (gi < lim) out[gi] = (float)sacc[i] * ACC_INV_SCALE;
    }
}

// Fallback: direct per-edge global atomics (correct, slow).
__global__ __launch_bounds__(256) void vb_edge_fallback(
    const float* __restrict__ vecs,
    const int*   __restrict__ centers,
    const int*   __restrict__ neighbors,
    const int*   __restrict__ species,
    const float* __restrict__ W_alch,
    const float* __restrict__ cemb,
    const float* __restrict__ Wc,
    float*       __restrict__ out,
    int E)
{
    __shared__ float sW2[3 * NRAD * 16];
    build_w2(sW2, cemb, Wc, W_alch, threadIdx.x, blockDim.x);
    __syncthreads();

    int e = blockIdx.x * blockDim.x + threadIdx.x;
    if (e >= E) return;
    float vx = vecs[3 * e + 0], vy = vecs[3 * e + 1], vz = vecs[3 * e + 2];
    int c = centers[e];
    int pair = species[c] * 4 + species[neighbors[e]];
    float g[3], t[3];
    if (!edge_math(vx, vy, vz, pair, sW2, g, t)) return;
    float* op = out + (size_t)c * 9;
    #pragma unroll
    for (int m = 0; m < 3; m++)
        #pragma unroll
        for (int o = 0; o < 3; o++)
            atomicAdd(op + m * 3 + o, g[m] * t[o]);
}

extern "C" void kernel_launch(void* const* d_in, const int* in_sizes, int n_in,
                              void* d_out, int out_size, void* d_ws, size_t ws_size,
                              hipStream_t stream) {
    const float* vecs      = (const float*)d_in[0];
    const int*   centers   = (const int*)d_in[1];
    const int*   neighbors = (const int*)d_in[2];
    const int*   species   = (const int*)d_in[3];
    const float* W_alch    = (const float*)d_in[6];
    const float* cemb      = (const float*)d_in[7];
    const float* Wc        = (const float*)d_in[8];
    float*       out       = (float*)d_out;

    int E = in_sizes[1];
    int A = in_sizes[3];
    int nbin    = (A + APB - 1) >> APB_SH;
    int nblocks = (E + PH1_REC - 1) / PH1_REC;

    // ws: [runoff nblocks*RS u16][payload nblocks*4096*16B]
    size_t ro_bytes = ((size_t)nblocks * RS * 2 + 255) & ~(size_t)255;
    size_t need = ro_bytes + (size_t)nblocks * PH1_REC * 16;

    if (nbin + 1 <= RS && nbin <= NBIN_PAD && nblocks < NROWS_PAD &&
        need <= ws_size) {
        unsigned short* runoff = (unsigned short*)d_ws;
        int4* payload = (int4*)((char*)d_ws + ro_bytes);

        vb_phase1<<<nblocks, PH1_BLK, 0, stream>>>(vecs, centers, neighbors,
                                                   species, W_alch, cemb, Wc,
                                                   runoff, payload, E, nbin);
        vb_phase2<<<nbin, P2_BLK, 0, stream>>>(runoff, payload, out, A, nblocks);
    } else {
        hipMemsetAsync(d_out, 0, (size_t)out_size * sizeof(float), stream);
        int grid = (E + 255) / 256;
        vb_edge_fallback<<<grid, 256, 0, stream>>>(vecs, centers, neighbors,
                                                   species, W_alch, cemb, Wc,
                                                   out, E);
    }
}